// Round 11
// baseline (253.443 us; speedup 1.0000x reference)
//
#include <hip/hip_runtime.h>
#include <hip/hip_bf16.h>

typedef __attribute__((ext_vector_type(4))) float f32x4;
typedef __attribute__((ext_vector_type(8))) short bf16x8;

#define MFMA16(a, b, c) __builtin_amdgcn_mfma_f32_16x16x32_bf16((a), (b), (c), 0, 0, 0)

// ---- LDS layout (bytes): W1 64K + params ~2.6K = 68128. 1024-thr blocks.
#define W1T_OFF 0        // 128 n-rows x 256 k bf16, XOR-swizzled 8-chunks
#define B1_OFF  65536
#define G1_OFF  66048
#define E1_OFF  66560
#define B2_OFF  67072
#define G2_OFF  67328
#define E2_OFF  67584
#define W3_OFF  67840
#define B3_OFF  68096
#define SMEM_BYTES 68128

__device__ __forceinline__ short f2bf(float x) {
  __hip_bfloat16 h = __float2bfloat16(x);
  return __builtin_bit_cast(short, h);
}

__device__ __forceinline__ bf16x8 pack8(f32x4 a, f32x4 b) {
  bf16x8 r;
  r[0] = f2bf(a[0]); r[1] = f2bf(a[1]); r[2] = f2bf(a[2]); r[3] = f2bf(a[3]);
  r[4] = f2bf(b[0]); r[5] = f2bf(b[1]); r[6] = f2bf(b[2]); r[7] = f2bf(b[3]);
  return r;
}

// GELU via logistic CDF fit, log2e folded: z / (1 + exp2(z*(c1 + c2 z^2))).
// |err| <~ 5e-4, under bf16 matmul noise (R4-R10 passed absmax 0.0078).
__device__ __forceinline__ float gelu_fast(float z) {
  float s = z * z;
  float y = z * __builtin_fmaf(-0.10180479f, s, -2.3048496f);
  float t = __builtin_amdgcn_exp2f(y);
  return z * __builtin_amdgcn_rcpf(1.0f + t);
}

// One-time weight prep into workspace:
//   w1i (32768 sh): W1 XOR-swizzled bf16 LDS image (verified R1-R10).
//   w2L (8192 sh): W2 pi-permuted fragments, lane-linear (verified R9/R10):
//        [(kb2*4+t)*512 + lane*8 + e] -> coalesced 1KB/wave loads, L1-hot.
//   forward pi: n -> k = (n>>5)*32 + ((n>>2)&3)*8 + ((n>>4)&1)*4 + (n&3)
__global__ __launch_bounds__(256) void prep_weights(
    const float* __restrict__ W1, const float* __restrict__ W2,
    short* __restrict__ w1i, short* __restrict__ w2L) {
  int idx = blockIdx.x * 256 + threadIdx.x;
  if (idx < 32768) {                       // W1 [k=256][n=128] row-major
    int k = idx >> 7, n = idx & 127;
    w1i[n * 256 + ((((k >> 3) ^ (n & 7)) << 3) | (k & 7))] = f2bf(W1[idx]);
  } else if (idx < 40960) {                // W2 [n=128][n2=64] row-major
    int j = idx - 32768;
    int n = j >> 6, n2 = j & 63;
    int kb2 = n >> 5;
    int qf = (n >> 2) & 3;
    int e = ((n >> 4) & 1) * 4 + (n & 3);
    int t = n2 >> 4, cc2 = n2 & 15;
    w2L[(kb2 * 4 + t) * 512 + (qf * 16 + cc2) * 8 + e] = f2bf(W2[j]);
  }
}

// One-time feature-table conversion f32 -> bf16 (R8-proven: FETCH 307->68 MB).
__global__ __launch_bounds__(256) void prep_feats(
    const float* __restrict__ f, short* __restrict__ o, int n8) {
  int idx = blockIdx.x * 256 + threadIdx.x;
  if (idx < n8) {
    f32x4 a = *(const f32x4*)(f + idx * 8);
    f32x4 b = *(const f32x4*)(f + idx * 8 + 4);
    *(bf16x8*)(o + idx * 8) = pack8(a, b);
  }
}

// Fused gather + (256->128 LN GELU) + (128->64 LN GELU) + (64->1).
// 16 waves/block (1024 thr), 16 edges/wave, 256-edge tiles.
// REGISTER MODEL (R2-R10, counter-verified): 1024-thr blocks ALWAYS get a
// 64-VGPR budget from hipcc (bare, (1024,4), (1024,8), waves_per_eu(2) --
// all measured 64). R10's body exceeded it by ~8-10 regs -> 24.6 MB scratch.
// This round caps transient pressure with sched_barrier(0) fences in both
// epilogues (param ds_reads otherwise batch-hoist: 16 f32x4 = 64 regs) so
// the body fits 64 cleanly. 512-thr blocks never exceed 8 waves/CU (R0/R6-R9)
// -> 1024-thr is the only occupancy route.
// pi-trick: layer-2 B operand = layer-1 accumulators (no H1 round-trip).
__global__ __launch_bounds__(1024) void mlp_fused(
    const short* __restrict__ drugb, const short* __restrict__ disb,
    const int* __restrict__ src, const int* __restrict__ dst,
    const short* __restrict__ w1i, const short* __restrict__ w2L,
    const float* __restrict__ b1, const float* __restrict__ g1, const float* __restrict__ be1,
    const float* __restrict__ b2, const float* __restrict__ g2, const float* __restrict__ be2,
    const float* __restrict__ W3, const float* __restrict__ b3,
    float* __restrict__ out, int E, int ntiles) {
  extern __shared__ char smem[];
  short* w1t = (short*)(smem + W1T_OFF);
  float* b1s = (float*)(smem + B1_OFF);
  float* g1s = (float*)(smem + G1_OFF);
  float* e1s = (float*)(smem + E1_OFF);
  float* b2s = (float*)(smem + B2_OFF);
  float* g2s = (float*)(smem + G2_OFF);
  float* e2s = (float*)(smem + E2_OFF);
  float* w3s = (float*)(smem + W3_OFF);
  float* b3s = (float*)(smem + B3_OFF);

  const int tid  = threadIdx.x;
  const int wave = tid >> 6;    // 0..15
  const int lane = tid & 63;
  const int q    = lane >> 4;   // quad (0..3)
  const int cc   = lane & 15;   // col-within-tile = edge slot

  // ---- one-time: linear copy of pre-swizzled 64KB W1 image into LDS ----
  #pragma unroll
  for (int o = 0; o < 4; ++o) {
    int s = (tid + o * 1024) * 8;          // shorts; 16B/thread/pass, 4 passes
    *(bf16x8*)(w1t + s) = *(const bf16x8*)(w1i + s);
  }
  if (tid < 128) { b1s[tid] = b1[tid]; g1s[tid] = g1[tid]; e1s[tid] = be1[tid]; }
  else if (tid < 192) { int j = tid - 128; b2s[j] = b2[j]; g2s[j] = g2[j]; e2s[j] = be2[j]; w3s[j] = W3[j]; }
  if (tid == 256) b3s[0] = b3[0];
  __syncthreads();

  // per-lane W2 fragment base (lane-linear global, coalesced, L1-hot)
  const short* w2p = w2L + (lane << 3);

  // ---- persistent loop over 256-edge tiles; waves free-run (no per-tile sync) ----
  for (int tile = blockIdx.x; tile < ntiles; tile += gridDim.x) {
    const int r  = tile * 256 + wave * 16 + cc;       // this lane's edge row
    const int rc = (r < E) ? r : (E - 1);             // clamp reads, guard writes
    const short* pd = drugb + (size_t)src[rc] * 128 + q * 8;
    const short* pq = disb  + (size_t)dst[rc] * 128 + q * 8;

    // ===== layer 1: [256]->[128], K=256, acc init = b1 (bias folded) =====
    f32x4 acc1[8];
    #pragma unroll
    for (int nt = 0; nt < 8; ++nt)
      acc1[nt] = *(const f32x4*)(b1s + nt * 16 + q * 4);

    bf16x8 u = *(const bf16x8*)pd;         // prefetch kb=0
    #pragma unroll 1
    for (int kb = 0; kb < 8; ++kb) {
      bf16x8 bfr = u;
      if (kb < 7) {                        // issue kb+1 load before kb's MFMAs
        const short* pn = (kb < 3) ? (pd + (kb + 1) * 32) : (pq + (kb - 3) * 32);
        u = *(const bf16x8*)pn;
      }
      const char* abase = (const char*)w1t + cc * 512 + ((((kb * 4 + q) ^ (cc & 7))) << 4);
      #pragma unroll
      for (int nt = 0; nt < 8; ++nt) {
        bf16x8 af = *(const bf16x8*)(abase + nt * 8192);
        acc1[nt] = MFMA16(af, bfr, acc1[nt]);
      }
    }

    // epilogue 1: LN over n=128, GELU, pack to bf16 hreg (acc1 dies here).
    // Per-h fencing: without it the 16 param ds_reads batch-hoist (64 regs)
    // and blow the 64-VGPR budget (R10's 24.6 MB scratch signature).
    bf16x8 hreg[4];
    {
      float s = 0.f, ss = 0.f;
      #pragma unroll
      for (int nt = 0; nt < 8; ++nt)
        #pragma unroll
        for (int j = 0; j < 4; ++j) { float v = acc1[nt][j]; s += v; ss += v * v; }
      s  += __shfl_xor(s, 16);  s  += __shfl_xor(s, 32);
      ss += __shfl_xor(ss, 16); ss += __shfl_xor(ss, 32);
      float mu   = s * 0.0078125f;
      float var  = ss * 0.0078125f - mu * mu;
      var = (var > 0.f) ? var : 0.f;
      float rstd = __builtin_amdgcn_rsqf(var + 1e-5f);

      #pragma unroll
      for (int h = 0; h < 4; ++h) {
        f32x4 glo = *(const f32x4*)(g1s + (2 * h) * 16 + q * 4);
        f32x4 elo = *(const f32x4*)(e1s + (2 * h) * 16 + q * 4);
        f32x4 ghi = *(const f32x4*)(g1s + (2 * h + 1) * 16 + q * 4);
        f32x4 ehi = *(const f32x4*)(e1s + (2 * h + 1) * 16 + q * 4);
        f32x4 a, b;
        #pragma unroll
        for (int j = 0; j < 4; ++j) {
          a[j] = gelu_fast(__builtin_fmaf((acc1[2 * h][j] - mu) * rstd, glo[j], elo[j]));
          b[j] = gelu_fast(__builtin_fmaf((acc1[2 * h + 1][j] - mu) * rstd, ghi[j], ehi[j]));
        }
        hreg[h] = pack8(a, b);
        __builtin_amdgcn_sched_barrier(0); // cap param transients at 16 regs
      }
    }

    // ===== layer 2: [128]->[64], B operand = hreg (pi-permuted, lane-local),
    // A fragments lane-linear from global (L1-hot), fenced per kb2 =====
    f32x4 acc2[4];
    #pragma unroll
    for (int t = 0; t < 4; ++t)
      acc2[t] = *(const f32x4*)(b2s + t * 16 + q * 4);

    #pragma unroll
    for (int kb2 = 0; kb2 < 4; ++kb2) {
      bf16x8 hb = hreg[kb2];
      #pragma unroll
      for (int t = 0; t < 4; ++t) {
        bf16x8 af = *(const bf16x8*)(w2p + (kb2 * 4 + t) * 512);
        acc2[t] = MFMA16(af, hb, acc2[t]);
      }
      __builtin_amdgcn_sched_barrier(0);   // cap in-flight W2 loads at 4 (16 regs)
    }

    // epilogue 2: LN over n=64, GELU, dot with W3, +b3, store (per-t fenced)
    {
      float s = 0.f, ss = 0.f;
      #pragma unroll
      for (int t = 0; t < 4; ++t)
        #pragma unroll
        for (int j = 0; j < 4; ++j) { float v = acc2[t][j]; s += v; ss += v * v; }
      s  += __shfl_xor(s, 16);  s  += __shfl_xor(s, 32);
      ss += __shfl_xor(ss, 16); ss += __shfl_xor(ss, 32);
      float mu   = s * 0.015625f;
      float var  = ss * 0.015625f - mu * mu;
      var = (var > 0.f) ? var : 0.f;
      float rstd = __builtin_amdgcn_rsqf(var + 1e-5f);

      float dot = 0.f;
      #pragma unroll
      for (int t = 0; t < 4; ++t) {
        f32x4 gv = *(const f32x4*)(g2s + t * 16 + q * 4);
        f32x4 ev = *(const f32x4*)(e2s + t * 16 + q * 4);
        f32x4 wv = *(const f32x4*)(w3s + t * 16 + q * 4);
        #pragma unroll
        for (int j = 0; j < 4; ++j) {
          float zz = __builtin_fmaf((acc2[t][j] - mu) * rstd, gv[j], ev[j]);
          dot = __builtin_fmaf(gelu_fast(zz), wv[j], dot);
        }
        __builtin_amdgcn_sched_barrier(0); // cap param transients at 12 regs
      }
      dot += __shfl_xor(dot, 16); dot += __shfl_xor(dot, 32);
      if (q == 0 && r < E) out[r] = dot + b3s[0];
    }
  }
}

extern "C" void kernel_launch(void* const* d_in, const int* in_sizes, int n_in,
                              void* d_out, int out_size, void* d_ws, size_t ws_size,
                              hipStream_t stream) {
  const float* drug = (const float*)d_in[0];
  const float* dis  = (const float*)d_in[1];
  const int*   src  = (const int*)d_in[2];
  const int*   dst  = (const int*)d_in[3];
  const float* W1   = (const float*)d_in[4];
  const float* b1   = (const float*)d_in[5];
  const float* g1   = (const float*)d_in[6];
  const float* be1  = (const float*)d_in[7];
  const float* W2   = (const float*)d_in[8];
  const float* b2   = (const float*)d_in[9];
  const float* g2   = (const float*)d_in[10];
  const float* be2  = (const float*)d_in[11];
  const float* W3   = (const float*)d_in[12];
  const float* b3   = (const float*)d_in[13];
  float* out = (float*)d_out;

  const int E      = in_sizes[2];
  const int ndrug8 = in_sizes[0] / 8;
  const int ndis8  = in_sizes[1] / 8;
  const int ntiles = (E + 255) / 256;      // 256-edge tiles (16 waves x 16 edges)

  short* w1i   = (short*)d_ws;             // 32768 shorts (full LDS image)
  short* w2L   = w1i + 32768;              // 8192 shorts (W2 lane-linear)
  short* drugb = w2L + 8192;               // bf16 feature tables
  short* disb  = drugb + (size_t)ndrug8 * 8;

  (void)hipFuncSetAttribute((const void*)mlp_fused,
                            hipFuncAttributeMaxDynamicSharedMemorySize, SMEM_BYTES);

  prep_weights<<<dim3(160), dim3(256), 0, stream>>>(W1, W2, w1i, w2L);
  prep_feats<<<dim3((ndrug8 + 255) / 256), dim3(256), 0, stream>>>(drug, drugb, ndrug8);
  prep_feats<<<dim3((ndis8 + 255) / 256), dim3(256), 0, stream>>>(dis, disb, ndis8);

  int grid = 512;                          // 2 WGs/CU upside if de-spill unlocks it
  if (ntiles < grid) grid = ntiles;
  mlp_fused<<<dim3(grid), dim3(1024), SMEM_BYTES, stream>>>(
      drugb, disb, src, dst, w1i, w2L,
      b1, g1, be1, b2, g2, be2, W3, b3, out, E, ntiles);
}

// Round 12
// 245.306 us; speedup vs baseline: 1.0332x; 1.0332x over previous
//
#include <hip/hip_runtime.h>
#include <hip/hip_bf16.h>

typedef __attribute__((ext_vector_type(4))) float f32x4;
typedef __attribute__((ext_vector_type(8))) short bf16x8;

#define MFMA16(a, b, c) __builtin_amdgcn_mfma_f32_16x16x32_bf16((a), (b), (c), 0, 0, 0)

// ---- LDS layout (bytes): W1 64K + H1 park 64K + params ~2.6K = 133664.
// 1 WG/CU (16 waves). H1 = wave-private 4KB park for the pi-permuted layer-1
// outputs: REPLACES the 16-reg hreg[] so the body fits 1024-thr's hard 64-VGPR
// budget (R10/R11: inherent live ~72 -> 24 MB scratch; fences proved useless).
#define W1T_OFF 0        // 128 n-rows x 256 k bf16, XOR-swizzled 8-chunks
#define H1_OFF  65536    // 16 waves x (4 frags x 64 lanes x 16B) = 65536
#define B1_OFF  131072
#define G1_OFF  131584
#define E1_OFF  132096
#define B2_OFF  132608
#define G2_OFF  132864
#define E2_OFF  133120
#define W3_OFF  133376
#define B3_OFF  133632
#define SMEM_BYTES 133664

__device__ __forceinline__ short f2bf(float x) {
  __hip_bfloat16 h = __float2bfloat16(x);
  return __builtin_bit_cast(short, h);
}

__device__ __forceinline__ bf16x8 pack8(f32x4 a, f32x4 b) {
  bf16x8 r;
  r[0] = f2bf(a[0]); r[1] = f2bf(a[1]); r[2] = f2bf(a[2]); r[3] = f2bf(a[3]);
  r[4] = f2bf(b[0]); r[5] = f2bf(b[1]); r[6] = f2bf(b[2]); r[7] = f2bf(b[3]);
  return r;
}

// GELU via logistic CDF fit, log2e folded: z / (1 + exp2(z*(c1 + c2 z^2))).
// |err| <~ 5e-4, under bf16 matmul noise (R4-R11 passed absmax 0.0078).
__device__ __forceinline__ float gelu_fast(float z) {
  float s = z * z;
  float y = z * __builtin_fmaf(-0.10180479f, s, -2.3048496f);
  float t = __builtin_amdgcn_exp2f(y);
  return z * __builtin_amdgcn_rcpf(1.0f + t);
}

// One-time weight prep into workspace:
//   w1i (32768 sh): W1 XOR-swizzled bf16 LDS image (verified R1-R11).
//   w2L (8192 sh): W2 pi-permuted fragments, lane-linear (verified R9-R11):
//        [(kb2*4+t)*512 + lane*8 + e] -> coalesced 1KB/wave loads, L1-hot.
//   forward pi: n -> k = (n>>5)*32 + ((n>>2)&3)*8 + ((n>>4)&1)*4 + (n&3)
__global__ __launch_bounds__(256) void prep_weights(
    const float* __restrict__ W1, const float* __restrict__ W2,
    short* __restrict__ w1i, short* __restrict__ w2L) {
  int idx = blockIdx.x * 256 + threadIdx.x;
  if (idx < 32768) {                       // W1 [k=256][n=128] row-major
    int k = idx >> 7, n = idx & 127;
    w1i[n * 256 + ((((k >> 3) ^ (n & 7)) << 3) | (k & 7))] = f2bf(W1[idx]);
  } else if (idx < 40960) {                // W2 [n=128][n2=64] row-major
    int j = idx - 32768;
    int n = j >> 6, n2 = j & 63;
    int kb2 = n >> 5;
    int qf = (n >> 2) & 3;
    int e = ((n >> 4) & 1) * 4 + (n & 3);
    int t = n2 >> 4, cc2 = n2 & 15;
    w2L[(kb2 * 4 + t) * 512 + (qf * 16 + cc2) * 8 + e] = f2bf(W2[j]);
  }
}

// One-time feature-table conversion f32 -> bf16 (R8-proven: FETCH 307->68 MB).
__global__ __launch_bounds__(256) void prep_feats(
    const float* __restrict__ f, short* __restrict__ o, int n8) {
  int idx = blockIdx.x * 256 + threadIdx.x;
  if (idx < n8) {
    f32x4 a = *(const f32x4*)(f + idx * 8);
    f32x4 b = *(const f32x4*)(f + idx * 8 + 4);
    *(bf16x8*)(o + idx * 8) = pack8(a, b);
  }
}

// Fused gather + (256->128 LN GELU) + (128->64 LN GELU) + (64->1).
// 16 waves/block (1024 thr), 16 edges/wave, 256-edge tiles, 1 WG/CU.
// REGISTER MODEL (R2-R11, counter-verified): 1024-thr = hard 64-VGPR budget
// (bare / (1024,4) / (1024,8) / waves_per_eu(2): all measured 64); 512-thr
// never exceeds 8 waves/CU. Body's inherent live set was ~72 (R8@512thr) ->
// under 64 the allocator scratch-spilled 24 MB/dispatch (R10/R11; sched
// fences changed nothing). Fix: evict hreg[4] (16 regs) to a wave-private
// LDS park -- pi-permutation makes the park lane-local (plain b128 write/
// read at lane*16, no swizzle/shuffle/barrier; 2-way bank alias = free).
__global__ __launch_bounds__(1024) void mlp_fused(
    const short* __restrict__ drugb, const short* __restrict__ disb,
    const int* __restrict__ src, const int* __restrict__ dst,
    const short* __restrict__ w1i, const short* __restrict__ w2L,
    const float* __restrict__ b1, const float* __restrict__ g1, const float* __restrict__ be1,
    const float* __restrict__ b2, const float* __restrict__ g2, const float* __restrict__ be2,
    const float* __restrict__ W3, const float* __restrict__ b3,
    float* __restrict__ out, int E, int ntiles) {
  extern __shared__ char smem[];
  short* w1t = (short*)(smem + W1T_OFF);
  float* b1s = (float*)(smem + B1_OFF);
  float* g1s = (float*)(smem + G1_OFF);
  float* e1s = (float*)(smem + E1_OFF);
  float* b2s = (float*)(smem + B2_OFF);
  float* g2s = (float*)(smem + G2_OFF);
  float* e2s = (float*)(smem + E2_OFF);
  float* w3s = (float*)(smem + W3_OFF);
  float* b3s = (float*)(smem + B3_OFF);

  const int tid  = threadIdx.x;
  const int wave = tid >> 6;    // 0..15
  const int lane = tid & 63;
  const int q    = lane >> 4;   // quad (0..3)
  const int cc   = lane & 15;   // col-within-tile = edge slot

  // wave-private park slot: 4 frags x 16B per lane
  short* h1w = (short*)(smem + H1_OFF) + wave * 2048 + lane * 8;

  // ---- one-time: linear copy of pre-swizzled 64KB W1 image into LDS ----
  #pragma unroll
  for (int o = 0; o < 4; ++o) {
    int s = (tid + o * 1024) * 8;          // shorts; 16B/thread/pass, 4 passes
    *(bf16x8*)(w1t + s) = *(const bf16x8*)(w1i + s);
  }
  if (tid < 128) { b1s[tid] = b1[tid]; g1s[tid] = g1[tid]; e1s[tid] = be1[tid]; }
  else if (tid < 192) { int j = tid - 128; b2s[j] = b2[j]; g2s[j] = g2[j]; e2s[j] = be2[j]; w3s[j] = W3[j]; }
  if (tid == 256) b3s[0] = b3[0];
  __syncthreads();

  // per-lane W2 fragment base (lane-linear global, coalesced, L1-hot)
  const short* w2p = w2L + (lane << 3);

  // ---- persistent loop over 256-edge tiles; waves free-run (no per-tile sync) ----
  for (int tile = blockIdx.x; tile < ntiles; tile += gridDim.x) {
    const int r  = tile * 256 + wave * 16 + cc;       // this lane's edge row
    const int rc = (r < E) ? r : (E - 1);             // clamp reads, guard writes
    const short* pd = drugb + (size_t)src[rc] * 128 + q * 8;
    const short* pq = disb  + (size_t)dst[rc] * 128 + q * 8;

    // ===== layer 1: [256]->[128], K=256, acc init = b1 (bias folded) =====
    f32x4 acc1[8];
    #pragma unroll
    for (int nt = 0; nt < 8; ++nt)
      acc1[nt] = *(const f32x4*)(b1s + nt * 16 + q * 4);

    bf16x8 u = *(const bf16x8*)pd;         // prefetch kb=0
    #pragma unroll 1
    for (int kb = 0; kb < 8; ++kb) {
      bf16x8 bfr = u;
      if (kb < 7) {                        // issue kb+1 load before kb's MFMAs
        const short* pn = (kb < 3) ? (pd + (kb + 1) * 32) : (pq + (kb - 3) * 32);
        u = *(const bf16x8*)pn;
      }
      const char* abase = (const char*)w1t + cc * 512 + ((((kb * 4 + q) ^ (cc & 7))) << 4);
      #pragma unroll
      for (int nt = 0; nt < 8; ++nt) {
        bf16x8 af = *(const bf16x8*)(abase + nt * 8192);
        acc1[nt] = MFMA16(af, bfr, acc1[nt]);
      }
    }

    // epilogue 1: LN over n=128, GELU, pack bf16 -> wave-private LDS park.
    // Per-h: acc1[2h],acc1[2h+1] die immediately after the park write ->
    // live set shrinks as the loop runs; no hreg[] array exists.
    {
      float s = 0.f, ss = 0.f;
      #pragma unroll
      for (int nt = 0; nt < 8; ++nt)
        #pragma unroll
        for (int j = 0; j < 4; ++j) { float v = acc1[nt][j]; s += v; ss += v * v; }
      s  += __shfl_xor(s, 16);  s  += __shfl_xor(s, 32);
      ss += __shfl_xor(ss, 16); ss += __shfl_xor(ss, 32);
      float mu   = s * 0.0078125f;
      float var  = ss * 0.0078125f - mu * mu;
      var = (var > 0.f) ? var : 0.f;
      float rstd = __builtin_amdgcn_rsqf(var + 1e-5f);

      #pragma unroll
      for (int h = 0; h < 4; ++h) {
        f32x4 glo = *(const f32x4*)(g1s + (2 * h) * 16 + q * 4);
        f32x4 elo = *(const f32x4*)(e1s + (2 * h) * 16 + q * 4);
        f32x4 ghi = *(const f32x4*)(g1s + (2 * h + 1) * 16 + q * 4);
        f32x4 ehi = *(const f32x4*)(e1s + (2 * h + 1) * 16 + q * 4);
        f32x4 a, b;
        #pragma unroll
        for (int j = 0; j < 4; ++j) {
          a[j] = gelu_fast(__builtin_fmaf((acc1[2 * h][j] - mu) * rstd, glo[j], elo[j]));
          b[j] = gelu_fast(__builtin_fmaf((acc1[2 * h + 1][j] - mu) * rstd, ghi[j], ehi[j]));
        }
        *(bf16x8*)(h1w + h * 512) = pack8(a, b);      // park (lane-private)
        __builtin_amdgcn_sched_barrier(0);
      }
    }
    // forbid store-to-load forwarding of the park (would resurrect 16 regs)
    asm volatile("" ::: "memory");

    // ===== layer 2: [128]->[64], B operand read back from the park,
    // A fragments lane-linear from global (L1-hot), fenced per kb2 =====
    f32x4 acc2[4];
    #pragma unroll
    for (int t = 0; t < 4; ++t)
      acc2[t] = *(const f32x4*)(b2s + t * 16 + q * 4);

    #pragma unroll
    for (int kb2 = 0; kb2 < 4; ++kb2) {
      bf16x8 hb = *(const bf16x8*)(h1w + kb2 * 512);  // un-park (lane-private)
      #pragma unroll
      for (int t = 0; t < 4; ++t) {
        bf16x8 af = *(const bf16x8*)(w2p + (kb2 * 4 + t) * 512);
        acc2[t] = MFMA16(af, hb, acc2[t]);
      }
      __builtin_amdgcn_sched_barrier(0);   // cap in-flight W2 loads at 4 (16 regs)
    }

    // epilogue 2: LN over n=64, GELU, dot with W3, +b3, store (per-t fenced:
    // 12 param vectors would otherwise hoist to 48 regs against acc2's 16)
    {
      float s = 0.f, ss = 0.f;
      #pragma unroll
      for (int t = 0; t < 4; ++t)
        #pragma unroll
        for (int j = 0; j < 4; ++j) { float v = acc2[t][j]; s += v; ss += v * v; }
      s  += __shfl_xor(s, 16);  s  += __shfl_xor(s, 32);
      ss += __shfl_xor(ss, 16); ss += __shfl_xor(ss, 32);
      float mu   = s * 0.015625f;
      float var  = ss * 0.015625f - mu * mu;
      var = (var > 0.f) ? var : 0.f;
      float rstd = __builtin_amdgcn_rsqf(var + 1e-5f);

      float dot = 0.f;
      #pragma unroll
      for (int t = 0; t < 4; ++t) {
        f32x4 gv = *(const f32x4*)(g2s + t * 16 + q * 4);
        f32x4 ev = *(const f32x4*)(e2s + t * 16 + q * 4);
        f32x4 wv = *(const f32x4*)(w3s + t * 16 + q * 4);
        #pragma unroll
        for (int j = 0; j < 4; ++j) {
          float zz = __builtin_fmaf((acc2[t][j] - mu) * rstd, gv[j], ev[j]);
          dot = __builtin_fmaf(gelu_fast(zz), wv[j], dot);
        }
        __builtin_amdgcn_sched_barrier(0);
      }
      dot += __shfl_xor(dot, 16); dot += __shfl_xor(dot, 32);
      if (q == 0 && r < E) out[r] = dot + b3s[0];
    }
  }
}

extern "C" void kernel_launch(void* const* d_in, const int* in_sizes, int n_in,
                              void* d_out, int out_size, void* d_ws, size_t ws_size,
                              hipStream_t stream) {
  const float* drug = (const float*)d_in[0];
  const float* dis  = (const float*)d_in[1];
  const int*   src  = (const int*)d_in[2];
  const int*   dst  = (const int*)d_in[3];
  const float* W1   = (const float*)d_in[4];
  const float* b1   = (const float*)d_in[5];
  const float* g1   = (const float*)d_in[6];
  const float* be1  = (const float*)d_in[7];
  const float* W2   = (const float*)d_in[8];
  const float* b2   = (const float*)d_in[9];
  const float* g2   = (const float*)d_in[10];
  const float* be2  = (const float*)d_in[11];
  const float* W3   = (const float*)d_in[12];
  const float* b3   = (const float*)d_in[13];
  float* out = (float*)d_out;

  const int E      = in_sizes[2];
  const int ndrug8 = in_sizes[0] / 8;
  const int ndis8  = in_sizes[1] / 8;
  const int ntiles = (E + 255) / 256;      // 256-edge tiles (16 waves x 16 edges)

  short* w1i   = (short*)d_ws;             // 32768 shorts (full LDS image)
  short* w2L   = w1i + 32768;              // 8192 shorts (W2 lane-linear)
  short* drugb = w2L + 8192;               // bf16 feature tables
  short* disb  = drugb + (size_t)ndrug8 * 8;

  (void)hipFuncSetAttribute((const void*)mlp_fused,
                            hipFuncAttributeMaxDynamicSharedMemorySize, SMEM_BYTES);

  prep_weights<<<dim3(160), dim3(256), 0, stream>>>(W1, W2, w1i, w2L);
  prep_feats<<<dim3((ndrug8 + 255) / 256), dim3(256), 0, stream>>>(drug, drugb, ndrug8);
  prep_feats<<<dim3((ndis8 + 255) / 256), dim3(256), 0, stream>>>(dis, disb, ndis8);

  int grid = 256;                          // persistent: 1 WG/CU (LDS 130.5K)
  if (ntiles < grid) grid = ntiles;
  mlp_fused<<<dim3(grid), dim3(1024), SMEM_BYTES, stream>>>(
      drugb, disb, src, dst, w1i, w2L,
      b1, g1, be1, b2, g2, be2, W3, b3, out, E, ntiles);
}

// Round 13
// 237.719 us; speedup vs baseline: 1.0661x; 1.0319x over previous
//
#include <hip/hip_runtime.h>
#include <hip/hip_bf16.h>

typedef __attribute__((ext_vector_type(4))) float f32x4;
typedef __attribute__((ext_vector_type(8))) short bf16x8;

#define MFMA16(a, b, c) __builtin_amdgcn_mfma_f32_16x16x32_bf16((a), (b), (c), 0, 0, 0)

// ---- LDS layout (bytes): W1 64K + params ~2.6K = 68128 (R7/R8-proven).
#define W1T_OFF 0        // 128 n-rows x 256 k bf16, XOR-swizzled 8-chunks
#define B1_OFF  65536
#define G1_OFF  66048
#define E1_OFF  66560
#define B2_OFF  67072
#define G2_OFF  67328
#define E2_OFF  67584
#define W3_OFF  67840
#define B3_OFF  68096
#define SMEM_BYTES 68128

__device__ __forceinline__ short f2bf(float x) {
  __hip_bfloat16 h = __float2bfloat16(x);
  return __builtin_bit_cast(short, h);
}

__device__ __forceinline__ bf16x8 pack8(f32x4 a, f32x4 b) {
  bf16x8 r;
  r[0] = f2bf(a[0]); r[1] = f2bf(a[1]); r[2] = f2bf(a[2]); r[3] = f2bf(a[3]);
  r[4] = f2bf(b[0]); r[5] = f2bf(b[1]); r[6] = f2bf(b[2]); r[7] = f2bf(b[3]);
  return r;
}

// GELU via logistic CDF fit, log2e folded: z / (1 + exp2(z*(c1 + c2 z^2))).
// |err| <~ 5e-4, under bf16 matmul noise (R4-R12 passed absmax 0.0078).
__device__ __forceinline__ float gelu_fast(float z) {
  float s = z * z;
  float y = z * __builtin_fmaf(-0.10180479f, s, -2.3048496f);
  float t = __builtin_amdgcn_exp2f(y);
  return z * __builtin_amdgcn_rcpf(1.0f + t);
}

// One-time weight prep into workspace:
//   w1i (32768 sh): W1 XOR-swizzled bf16 LDS image (verified R1-R12).
//   w2L (8192 sh): W2 pi-permuted fragments, lane-linear (verified R9-R12):
//        [(kb2*4+t)*512 + lane*8 + e] -> coalesced 1KB/wave loads, L1-hot.
//   forward pi: n -> k = (n>>5)*32 + ((n>>2)&3)*8 + ((n>>4)&1)*4 + (n&3)
__global__ __launch_bounds__(256) void prep_weights(
    const float* __restrict__ W1, const float* __restrict__ W2,
    short* __restrict__ w1i, short* __restrict__ w2L) {
  int idx = blockIdx.x * 256 + threadIdx.x;
  if (idx < 32768) {                       // W1 [k=256][n=128] row-major
    int k = idx >> 7, n = idx & 127;
    w1i[n * 256 + ((((k >> 3) ^ (n & 7)) << 3) | (k & 7))] = f2bf(W1[idx]);
  } else if (idx < 40960) {                // W2 [n=128][n2=64] row-major
    int j = idx - 32768;
    int n = j >> 6, n2 = j & 63;
    int kb2 = n >> 5;
    int qf = (n >> 2) & 3;
    int e = ((n >> 4) & 1) * 4 + (n & 3);
    int t = n2 >> 4, cc2 = n2 & 15;
    w2L[(kb2 * 4 + t) * 512 + (qf * 16 + cc2) * 8 + e] = f2bf(W2[j]);
  }
}

// One-time feature-table conversion f32 -> bf16 (R8-proven: FETCH 307->68 MB).
__global__ __launch_bounds__(256) void prep_feats(
    const float* __restrict__ f, short* __restrict__ o, int n8) {
  int idx = blockIdx.x * 256 + threadIdx.x;
  if (idx < n8) {
    f32x4 a = *(const f32x4*)(f + idx * 8);
    f32x4 b = *(const f32x4*)(f + idx * 8 + 4);
    *(bf16x8*)(o + idx * 8) = pack8(a, b);
  }
}

// Fused gather + (256->128 LN GELU) + (128->64 LN GELU) + (64->1).
// 8 waves/block (512 thr), mt=2: 32 edges/wave, 256-edge tiles.
// WHY THIS SHAPE (R8-R12 evidence): R8 (512thr, mt=1) hit VALU 55% with only
// 2 waves/SIMD -- same as R12's 4 waves/SIMD -- so per-wave ILP, not wave
// count, fills the pipes. mt=2 doubles independent MFMA/gather chains and
// HALVES per-edge ds_read/W2/param traffic (each af/param feeds 2 MFMAs).
// Register budget: (512,2) = 128 regs (proven); mt=2 body peaks ~100-112.
// 1024-thr rejected: hard 64-reg budget (R10-R12: inherent live ~72).
// pi-trick: layer-2 B operand = layer-1 accumulators (no H1 round-trip).
__global__ __launch_bounds__(512, 2) void mlp_fused(
    const short* __restrict__ drugb, const short* __restrict__ disb,
    const int* __restrict__ src, const int* __restrict__ dst,
    const short* __restrict__ w1i, const short* __restrict__ w2L,
    const float* __restrict__ b1, const float* __restrict__ g1, const float* __restrict__ be1,
    const float* __restrict__ b2, const float* __restrict__ g2, const float* __restrict__ be2,
    const float* __restrict__ W3, const float* __restrict__ b3,
    float* __restrict__ out, int E, int ntiles) {
  extern __shared__ char smem[];
  short* w1t = (short*)(smem + W1T_OFF);
  float* b1s = (float*)(smem + B1_OFF);
  float* g1s = (float*)(smem + G1_OFF);
  float* e1s = (float*)(smem + E1_OFF);
  float* b2s = (float*)(smem + B2_OFF);
  float* g2s = (float*)(smem + G2_OFF);
  float* e2s = (float*)(smem + E2_OFF);
  float* w3s = (float*)(smem + W3_OFF);
  float* b3s = (float*)(smem + B3_OFF);

  const int tid  = threadIdx.x;
  const int wave = tid >> 6;    // 0..7
  const int lane = tid & 63;
  const int q    = lane >> 4;   // quad (0..3)
  const int cc   = lane & 15;   // col-within-tile = edge slot

  // ---- one-time: linear copy of pre-swizzled 64KB W1 image into LDS ----
  #pragma unroll
  for (int o = 0; o < 8; ++o) {
    int s = (tid + o * 512) * 8;           // shorts; 16B/thread/pass, 8 passes
    *(bf16x8*)(w1t + s) = *(const bf16x8*)(w1i + s);
  }
  if (tid < 128) { b1s[tid] = b1[tid]; g1s[tid] = g1[tid]; e1s[tid] = be1[tid]; }
  else if (tid < 192) { int j = tid - 128; b2s[j] = b2[j]; g2s[j] = g2[j]; e2s[j] = be2[j]; w3s[j] = W3[j]; }
  if (tid == 256) b3s[0] = b3[0];
  __syncthreads();

  // per-lane W2 fragment base (lane-linear global, coalesced, L1-hot)
  const short* w2p = w2L + (lane << 3);

  // ---- persistent loop over 256-edge tiles; waves free-run (no per-tile sync) ----
  for (int tile = blockIdx.x; tile < ntiles; tile += gridDim.x) {
    const int r0  = tile * 256 + wave * 32 + cc;      // mt=0 edge; mt=1 = r0+16
    const int rc0 = (r0 < E) ? r0 : (E - 1);
    const int rc1 = (r0 + 16 < E) ? (r0 + 16) : (E - 1);
    const short* pd0 = drugb + (size_t)src[rc0] * 128 + q * 8;
    const short* pq0 = disb  + (size_t)dst[rc0] * 128 + q * 8;
    const short* pd1 = drugb + (size_t)src[rc1] * 128 + q * 8;
    const short* pq1 = disb  + (size_t)dst[rc1] * 128 + q * 8;

    // ===== layer 1: [256]->[128], K=256, acc init = b1 (bias folded) =====
    f32x4 acc1[8][2];
    #pragma unroll
    for (int nt = 0; nt < 8; ++nt) {
      f32x4 bv = *(const f32x4*)(b1s + nt * 16 + q * 4);
      acc1[nt][0] = bv;
      acc1[nt][1] = bv;
    }

    bf16x8 u0 = *(const bf16x8*)pd0;       // prefetch kb=0, both streams
    bf16x8 u1 = *(const bf16x8*)pd1;
    #pragma unroll 1
    for (int kb = 0; kb < 8; ++kb) {
      bf16x8 f0 = u0, f1 = u1;
      if (kb < 7) {                        // issue kb+1 loads before kb's MFMAs
        const short* pn0 = (kb < 3) ? (pd0 + (kb + 1) * 32) : (pq0 + (kb - 3) * 32);
        const short* pn1 = (kb < 3) ? (pd1 + (kb + 1) * 32) : (pq1 + (kb - 3) * 32);
        u0 = *(const bf16x8*)pn0;
        u1 = *(const bf16x8*)pn1;
      }
      const char* abase = (const char*)w1t + cc * 512 + ((((kb * 4 + q) ^ (cc & 7))) << 4);
      #pragma unroll
      for (int nt = 0; nt < 8; ++nt) {
        bf16x8 af = *(const bf16x8*)(abase + nt * 8192);   // one read, two MFMAs
        acc1[nt][0] = MFMA16(af, f0, acc1[nt][0]);
        acc1[nt][1] = MFMA16(af, f1, acc1[nt][1]);
      }
    }

    // epilogue 1: per-edge-group LN over n=128, GELU, pack to hreg.
    // Both mt stats first, then one shared param pass (params read once).
    bf16x8 hreg[4][2];
    {
      float s0 = 0.f, ss0 = 0.f, s1 = 0.f, ss1 = 0.f;
      #pragma unroll
      for (int nt = 0; nt < 8; ++nt)
        #pragma unroll
        for (int j = 0; j < 4; ++j) {
          float v0 = acc1[nt][0][j]; s0 += v0; ss0 += v0 * v0;
          float v1 = acc1[nt][1][j]; s1 += v1; ss1 += v1 * v1;
        }
      s0  += __shfl_xor(s0, 16);  s0  += __shfl_xor(s0, 32);
      ss0 += __shfl_xor(ss0, 16); ss0 += __shfl_xor(ss0, 32);
      s1  += __shfl_xor(s1, 16);  s1  += __shfl_xor(s1, 32);
      ss1 += __shfl_xor(ss1, 16); ss1 += __shfl_xor(ss1, 32);
      float mu0 = s0 * 0.0078125f, mu1 = s1 * 0.0078125f;
      float va0 = ss0 * 0.0078125f - mu0 * mu0;
      float va1 = ss1 * 0.0078125f - mu1 * mu1;
      va0 = (va0 > 0.f) ? va0 : 0.f;
      va1 = (va1 > 0.f) ? va1 : 0.f;
      float rs0 = __builtin_amdgcn_rsqf(va0 + 1e-5f);
      float rs1 = __builtin_amdgcn_rsqf(va1 + 1e-5f);

      #pragma unroll
      for (int h = 0; h < 4; ++h) {
        f32x4 glo = *(const f32x4*)(g1s + (2 * h) * 16 + q * 4);
        f32x4 elo = *(const f32x4*)(e1s + (2 * h) * 16 + q * 4);
        f32x4 ghi = *(const f32x4*)(g1s + (2 * h + 1) * 16 + q * 4);
        f32x4 ehi = *(const f32x4*)(e1s + (2 * h + 1) * 16 + q * 4);
        f32x4 a0, b0, a1, b1v;
        #pragma unroll
        for (int j = 0; j < 4; ++j) {
          a0[j]  = gelu_fast(__builtin_fmaf((acc1[2 * h][0][j]     - mu0) * rs0, glo[j], elo[j]));
          b0[j]  = gelu_fast(__builtin_fmaf((acc1[2 * h + 1][0][j] - mu0) * rs0, ghi[j], ehi[j]));
          a1[j]  = gelu_fast(__builtin_fmaf((acc1[2 * h][1][j]     - mu1) * rs1, glo[j], elo[j]));
          b1v[j] = gelu_fast(__builtin_fmaf((acc1[2 * h + 1][1][j] - mu1) * rs1, ghi[j], ehi[j]));
        }
        hreg[h][0] = pack8(a0, b0);
        hreg[h][1] = pack8(a1, b1v);
      }
    }

    // ===== layer 2: [128]->[64], B operands = hreg (pi-permuted, lane-local),
    // A fragments lane-linear from global (L1-hot), one load -> two MFMAs =====
    f32x4 acc2[4][2];
    #pragma unroll
    for (int t = 0; t < 4; ++t) {
      f32x4 bv = *(const f32x4*)(b2s + t * 16 + q * 4);
      acc2[t][0] = bv;
      acc2[t][1] = bv;
    }

    #pragma unroll
    for (int kb2 = 0; kb2 < 4; ++kb2) {
      bf16x8 h0 = hreg[kb2][0];
      bf16x8 h1 = hreg[kb2][1];
      #pragma unroll
      for (int t = 0; t < 4; ++t) {
        bf16x8 af = *(const bf16x8*)(w2p + (kb2 * 4 + t) * 512);
        acc2[t][0] = MFMA16(af, h0, acc2[t][0]);
        acc2[t][1] = MFMA16(af, h1, acc2[t][1]);
      }
      __builtin_amdgcn_sched_barrier(0);   // cap in-flight W2 loads at 4 (16 regs)
    }

    // epilogue 2: LN over n=64 per edge-group, GELU, dot with W3, +b3, store.
    // Shared param pass: each gv/ev/wv read once, feeds both edge-groups.
    {
      float s0 = 0.f, ss0 = 0.f, s1 = 0.f, ss1 = 0.f;
      #pragma unroll
      for (int t = 0; t < 4; ++t)
        #pragma unroll
        for (int j = 0; j < 4; ++j) {
          float v0 = acc2[t][0][j]; s0 += v0; ss0 += v0 * v0;
          float v1 = acc2[t][1][j]; s1 += v1; ss1 += v1 * v1;
        }
      s0  += __shfl_xor(s0, 16);  s0  += __shfl_xor(s0, 32);
      ss0 += __shfl_xor(ss0, 16); ss0 += __shfl_xor(ss0, 32);
      s1  += __shfl_xor(s1, 16);  s1  += __shfl_xor(s1, 32);
      ss1 += __shfl_xor(ss1, 16); ss1 += __shfl_xor(ss1, 32);
      float mu0 = s0 * 0.015625f, mu1 = s1 * 0.015625f;
      float va0 = ss0 * 0.015625f - mu0 * mu0;
      float va1 = ss1 * 0.015625f - mu1 * mu1;
      va0 = (va0 > 0.f) ? va0 : 0.f;
      va1 = (va1 > 0.f) ? va1 : 0.f;
      float rs0 = __builtin_amdgcn_rsqf(va0 + 1e-5f);
      float rs1 = __builtin_amdgcn_rsqf(va1 + 1e-5f);

      float dot0 = 0.f, dot1 = 0.f;
      #pragma unroll
      for (int t = 0; t < 4; ++t) {
        f32x4 gv = *(const f32x4*)(g2s + t * 16 + q * 4);
        f32x4 ev = *(const f32x4*)(e2s + t * 16 + q * 4);
        f32x4 wv = *(const f32x4*)(w3s + t * 16 + q * 4);
        #pragma unroll
        for (int j = 0; j < 4; ++j) {
          float z0 = __builtin_fmaf((acc2[t][0][j] - mu0) * rs0, gv[j], ev[j]);
          float z1 = __builtin_fmaf((acc2[t][1][j] - mu1) * rs1, gv[j], ev[j]);
          dot0 = __builtin_fmaf(gelu_fast(z0), wv[j], dot0);
          dot1 = __builtin_fmaf(gelu_fast(z1), wv[j], dot1);
        }
      }
      dot0 += __shfl_xor(dot0, 16); dot0 += __shfl_xor(dot0, 32);
      dot1 += __shfl_xor(dot1, 16); dot1 += __shfl_xor(dot1, 32);
      if (q == 0) {
        float bias3 = b3s[0];
        if (r0 < E)      out[r0]      = dot0 + bias3;
        if (r0 + 16 < E) out[r0 + 16] = dot1 + bias3;
      }
    }
  }
}

extern "C" void kernel_launch(void* const* d_in, const int* in_sizes, int n_in,
                              void* d_out, int out_size, void* d_ws, size_t ws_size,
                              hipStream_t stream) {
  const float* drug = (const float*)d_in[0];
  const float* dis  = (const float*)d_in[1];
  const int*   src  = (const int*)d_in[2];
  const int*   dst  = (const int*)d_in[3];
  const float* W1   = (const float*)d_in[4];
  const float* b1   = (const float*)d_in[5];
  const float* g1   = (const float*)d_in[6];
  const float* be1  = (const float*)d_in[7];
  const float* W2   = (const float*)d_in[8];
  const float* b2   = (const float*)d_in[9];
  const float* g2   = (const float*)d_in[10];
  const float* be2  = (const float*)d_in[11];
  const float* W3   = (const float*)d_in[12];
  const float* b3   = (const float*)d_in[13];
  float* out = (float*)d_out;

  const int E      = in_sizes[2];
  const int ndrug8 = in_sizes[0] / 8;
  const int ndis8  = in_sizes[1] / 8;
  const int ntiles = (E + 255) / 256;      // 256-edge tiles (8 waves x 32 edges)

  short* w1i   = (short*)d_ws;             // 32768 shorts (full LDS image)
  short* w2L   = w1i + 32768;              // 8192 shorts (W2 lane-linear)
  short* drugb = w2L + 8192;               // bf16 feature tables
  short* disb  = drugb + (size_t)ndrug8 * 8;

  (void)hipFuncSetAttribute((const void*)mlp_fused,
                            hipFuncAttributeMaxDynamicSharedMemorySize, SMEM_BYTES);

  prep_weights<<<dim3(160), dim3(256), 0, stream>>>(W1, W2, w1i, w2L);
  prep_feats<<<dim3((ndrug8 + 255) / 256), dim3(256), 0, stream>>>(drug, drugb, ndrug8);
  prep_feats<<<dim3((ndis8 + 255) / 256), dim3(256), 0, stream>>>(dis, disb, ndis8);

  int grid = 512;
  if (ntiles < grid) grid = ntiles;
  mlp_fused<<<dim3(grid), dim3(512), SMEM_BYTES, stream>>>(
      drugb, disb, src, dst, w1i, w2L,
      b1, g1, be1, b2, g2, be2, W3, b3, out, E, ntiles);
}

// Round 14
// 234.576 us; speedup vs baseline: 1.0804x; 1.0134x over previous
//
#include <hip/hip_runtime.h>
#include <hip/hip_bf16.h>

typedef __attribute__((ext_vector_type(4))) float f32x4;
typedef __attribute__((ext_vector_type(8))) short bf16x8;

#define MFMA16(a, b, c) __builtin_amdgcn_mfma_f32_16x16x32_bf16((a), (b), (c), 0, 0, 0)

// ---- LDS layout (bytes): W1 64K + params ~2.6K = 68128 (R7+-proven).
#define W1T_OFF 0        // 128 n-rows x 256 k bf16, XOR-swizzled 8-chunks
#define B1_OFF  65536
#define G1_OFF  66048
#define E1_OFF  66560
#define B2_OFF  67072
#define G2_OFF  67328
#define E2_OFF  67584
#define W3_OFF  67840
#define B3_OFF  68096
#define SMEM_BYTES 68128

__device__ __forceinline__ short f2bf(float x) {
  __hip_bfloat16 h = __float2bfloat16(x);
  return __builtin_bit_cast(short, h);
}

__device__ __forceinline__ bf16x8 pack8(f32x4 a, f32x4 b) {
  bf16x8 r;
  r[0] = f2bf(a[0]); r[1] = f2bf(a[1]); r[2] = f2bf(a[2]); r[3] = f2bf(a[3]);
  r[4] = f2bf(b[0]); r[5] = f2bf(b[1]); r[6] = f2bf(b[2]); r[7] = f2bf(b[3]);
  return r;
}

// GELU via logistic CDF fit, log2e folded: z / (1 + exp2(z*(c1 + c2 z^2))).
// |err| <~ 5e-4, under bf16 matmul noise (R4-R13 passed).
__device__ __forceinline__ float gelu_fast(float z) {
  float s = z * z;
  float y = z * __builtin_fmaf(-0.10180479f, s, -2.3048496f);
  float t = __builtin_amdgcn_exp2f(y);
  return z * __builtin_amdgcn_rcpf(1.0f + t);
}

// One-time weight prep into workspace (verified R9-R13):
//   w1i: W1 XOR-swizzled bf16 LDS image.
//   w2L: W2 pi-permuted fragments, lane-linear [(kb2*4+t)*512 + lane*8 + e].
//   forward pi: n -> k = (n>>5)*32 + ((n>>2)&3)*8 + ((n>>4)&1)*4 + (n&3)
__global__ __launch_bounds__(256) void prep_weights(
    const float* __restrict__ W1, const float* __restrict__ W2,
    short* __restrict__ w1i, short* __restrict__ w2L) {
  int idx = blockIdx.x * 256 + threadIdx.x;
  if (idx < 32768) {                       // W1 [k=256][n=128] row-major
    int k = idx >> 7, n = idx & 127;
    w1i[n * 256 + ((((k >> 3) ^ (n & 7)) << 3) | (k & 7))] = f2bf(W1[idx]);
  } else if (idx < 40960) {                // W2 [n=128][n2=64] row-major
    int j = idx - 32768;
    int n = j >> 6, n2 = j & 63;
    int kb2 = n >> 5;
    int qf = (n >> 2) & 3;
    int e = ((n >> 4) & 1) * 4 + (n & 3);
    int t = n2 >> 4, cc2 = n2 & 15;
    w2L[(kb2 * 4 + t) * 512 + (qf * 16 + cc2) * 8 + e] = f2bf(W2[j]);
  }
}

// One-time feature-table conversion f32 -> bf16 (R8-proven).
__global__ __launch_bounds__(256) void prep_feats(
    const float* __restrict__ f, short* __restrict__ o, int n8) {
  int idx = blockIdx.x * 256 + threadIdx.x;
  if (idx < n8) {
    f32x4 a = *(const f32x4*)(f + idx * 8);
    f32x4 b = *(const f32x4*)(f + idx * 8 + 4);
    *(bf16x8*)(o + idx * 8) = pack8(a, b);
  }
}

// Fused gather + (256->128 LN GELU) + (128->64 LN GELU) + (64->1).
// 8 waves/block (512 thr), mt=2 (32 edges/wave), 256-edge tiles.
// KEY INSIGHT (R0-R13): 512-thr blocks ALWAYS get 8 waves/CU = 2 waves/SIMD
// (measured at LDS 51-80K, VGPR 72-128 -- invariant). 2 waves/SIMD only needs
// <=256 VGPR/wave, so (512,1) frees the register ceiling AT ZERO OCCUPANCY
// COST. This round spends that headroom on a 4-deep gather prefetch ring
// (64 regs in flight): dependency distance 4 kb bodies ~300cy >= L2 latency,
// killing the per-kb stall that R12's counters showed (53% VALU / 27% idle).
// pi-trick: layer-2 B operand = layer-1 accumulators (no H1 round-trip).
__global__ __launch_bounds__(512, 1) void mlp_fused(
    const short* __restrict__ drugb, const short* __restrict__ disb,
    const int* __restrict__ src, const int* __restrict__ dst,
    const short* __restrict__ w1i, const short* __restrict__ w2L,
    const float* __restrict__ b1, const float* __restrict__ g1, const float* __restrict__ be1,
    const float* __restrict__ b2, const float* __restrict__ g2, const float* __restrict__ be2,
    const float* __restrict__ W3, const float* __restrict__ b3,
    float* __restrict__ out, int E, int ntiles) {
  extern __shared__ char smem[];
  short* w1t = (short*)(smem + W1T_OFF);
  float* b1s = (float*)(smem + B1_OFF);
  float* g1s = (float*)(smem + G1_OFF);
  float* e1s = (float*)(smem + E1_OFF);
  float* b2s = (float*)(smem + B2_OFF);
  float* g2s = (float*)(smem + G2_OFF);
  float* e2s = (float*)(smem + E2_OFF);
  float* w3s = (float*)(smem + W3_OFF);
  float* b3s = (float*)(smem + B3_OFF);

  const int tid  = threadIdx.x;
  const int wave = tid >> 6;    // 0..7
  const int lane = tid & 63;
  const int q    = lane >> 4;   // quad (0..3)
  const int cc   = lane & 15;   // col-within-tile = edge slot

  // ---- one-time: linear copy of pre-swizzled 64KB W1 image into LDS ----
  #pragma unroll
  for (int o = 0; o < 8; ++o) {
    int s = (tid + o * 512) * 8;           // shorts; 16B/thread/pass, 8 passes
    *(bf16x8*)(w1t + s) = *(const bf16x8*)(w1i + s);
  }
  if (tid < 128) { b1s[tid] = b1[tid]; g1s[tid] = g1[tid]; e1s[tid] = be1[tid]; }
  else if (tid < 192) { int j = tid - 128; b2s[j] = b2[j]; g2s[j] = g2[j]; e2s[j] = be2[j]; w3s[j] = W3[j]; }
  if (tid == 256) b3s[0] = b3[0];
  __syncthreads();

  // per-lane W2 fragment base (lane-linear global, coalesced, L1-hot)
  const short* w2p = w2L + (lane << 3);

  // ---- cross-tile index prefetch: first tile's gather indices up front ----
  int s0i = 0, d0i = 0, s1i = 0, d1i = 0;
  {
    int r0 = blockIdx.x * 256 + wave * 32 + cc;
    int rc0 = (r0 < E) ? r0 : (E - 1);
    int rc1 = (r0 + 16 < E) ? (r0 + 16) : (E - 1);
    s0i = src[rc0]; d0i = dst[rc0]; s1i = src[rc1]; d1i = dst[rc1];
  }

  // ---- persistent loop over 256-edge tiles; waves free-run (no per-tile sync) ----
  for (int tile = blockIdx.x; tile < ntiles; tile += gridDim.x) {
    const int r0 = tile * 256 + wave * 32 + cc;       // mt=0 edge; mt=1 = r0+16
    const short* pd0 = drugb + (size_t)s0i * 128 + q * 8;
    const short* pq0 = disb  + (size_t)d0i * 128 + q * 8;
    const short* pd1 = drugb + (size_t)s1i * 128 + q * 8;
    const short* pq1 = disb  + (size_t)d1i * 128 + q * 8;

    // prologue: fill the 4-deep ring (kb 0..3, both edge streams) -> 8 loads in flight
    bf16x8 u[4][2];
    #pragma unroll
    for (int i = 0; i < 4; ++i) {
      u[i][0] = *(const bf16x8*)(pd0 + i * 32);
      u[i][1] = *(const bf16x8*)(pd1 + i * 32);
    }

    // prefetch NEXT tile's gather indices (hides idx->gather chain at tile start)
    {
      int tn = tile + gridDim.x;
      if (tn < ntiles) {
        int rn  = tn * 256 + wave * 32 + cc;
        int rcn0 = (rn < E) ? rn : (E - 1);
        int rcn1 = (rn + 16 < E) ? (rn + 16) : (E - 1);
        s0i = src[rcn0]; d0i = dst[rcn0]; s1i = src[rcn1]; d1i = dst[rcn1];
      }
    }

    // ===== layer 1: [256]->[128], K=256, acc init = b1 (bias folded) =====
    f32x4 acc1[8][2];
    #pragma unroll
    for (int nt = 0; nt < 8; ++nt) {
      f32x4 bv = *(const f32x4*)(b1s + nt * 16 + q * 4);
      acc1[nt][0] = bv;
      acc1[nt][1] = bv;
    }

    #pragma unroll
    for (int kb = 0; kb < 8; ++kb) {
      bf16x8 f0 = u[kb & 3][0];
      bf16x8 f1 = u[kb & 3][1];
      if (kb < 4) {                        // refill slot with kb+4 (= pq + kb*32)
        u[kb & 3][0] = *(const bf16x8*)(pq0 + kb * 32);
        u[kb & 3][1] = *(const bf16x8*)(pq1 + kb * 32);
      }
      const char* abase = (const char*)w1t + cc * 512 + ((((kb * 4 + q) ^ (cc & 7))) << 4);
      #pragma unroll
      for (int nt = 0; nt < 8; ++nt) {
        bf16x8 af = *(const bf16x8*)(abase + nt * 8192);   // one read, two MFMAs
        acc1[nt][0] = MFMA16(af, f0, acc1[nt][0]);
        acc1[nt][1] = MFMA16(af, f1, acc1[nt][1]);
      }
    }

    // epilogue 1: per-edge-group LN over n=128 (affine-folded), GELU, pack to hreg
    bf16x8 hreg[4][2];
    {
      float s0 = 0.f, ss0 = 0.f, s1 = 0.f, ss1 = 0.f;
      #pragma unroll
      for (int nt = 0; nt < 8; ++nt)
        #pragma unroll
        for (int j = 0; j < 4; ++j) {
          float v0 = acc1[nt][0][j]; s0 += v0; ss0 += v0 * v0;
          float v1 = acc1[nt][1][j]; s1 += v1; ss1 += v1 * v1;
        }
      s0  += __shfl_xor(s0, 16);  s0  += __shfl_xor(s0, 32);
      ss0 += __shfl_xor(ss0, 16); ss0 += __shfl_xor(ss0, 32);
      s1  += __shfl_xor(s1, 16);  s1  += __shfl_xor(s1, 32);
      ss1 += __shfl_xor(ss1, 16); ss1 += __shfl_xor(ss1, 32);
      float mu0 = s0 * 0.0078125f, mu1 = s1 * 0.0078125f;
      float va0 = ss0 * 0.0078125f - mu0 * mu0;
      float va1 = ss1 * 0.0078125f - mu1 * mu1;
      va0 = (va0 > 0.f) ? va0 : 0.f;
      va1 = (va1 > 0.f) ? va1 : 0.f;
      float rs0 = __builtin_amdgcn_rsqf(va0 + 1e-5f);
      float rs1 = __builtin_amdgcn_rsqf(va1 + 1e-5f);

      #pragma unroll
      for (int h = 0; h < 4; ++h) {
        f32x4 glo = *(const f32x4*)(g1s + (2 * h) * 16 + q * 4);
        f32x4 elo = *(const f32x4*)(e1s + (2 * h) * 16 + q * 4);
        f32x4 ghi = *(const f32x4*)(g1s + (2 * h + 1) * 16 + q * 4);
        f32x4 ehi = *(const f32x4*)(e1s + (2 * h + 1) * 16 + q * 4);
        // LN affine fold: z = x*(g*rs) + (be - mu*(g*rs)) -> 1 fma/value
        f32x4 al0, cl0, al1, cl1, ah0, ch0, ah1, ch1;
        #pragma unroll
        for (int j = 0; j < 4; ++j) {
          al0[j] = glo[j] * rs0; cl0[j] = __builtin_fmaf(-mu0, al0[j], elo[j]);
          al1[j] = glo[j] * rs1; cl1[j] = __builtin_fmaf(-mu1, al1[j], elo[j]);
          ah0[j] = ghi[j] * rs0; ch0[j] = __builtin_fmaf(-mu0, ah0[j], ehi[j]);
          ah1[j] = ghi[j] * rs1; ch1[j] = __builtin_fmaf(-mu1, ah1[j], ehi[j]);
        }
        f32x4 a0, b0, a1, b1v;
        #pragma unroll
        for (int j = 0; j < 4; ++j) {
          a0[j]  = gelu_fast(__builtin_fmaf(acc1[2 * h][0][j],     al0[j], cl0[j]));
          b0[j]  = gelu_fast(__builtin_fmaf(acc1[2 * h + 1][0][j], ah0[j], ch0[j]));
          a1[j]  = gelu_fast(__builtin_fmaf(acc1[2 * h][1][j],     al1[j], cl1[j]));
          b1v[j] = gelu_fast(__builtin_fmaf(acc1[2 * h + 1][1][j], ah1[j], ch1[j]));
        }
        hreg[h][0] = pack8(a0, b0);
        hreg[h][1] = pack8(a1, b1v);
      }
    }

    // ===== layer 2: [128]->[64], B operands = hreg (pi-permuted, lane-local),
    // A fragments lane-linear from global (L1-hot), fenced per kb2 =====
    f32x4 acc2[4][2];
    #pragma unroll
    for (int t = 0; t < 4; ++t) {
      f32x4 bv = *(const f32x4*)(b2s + t * 16 + q * 4);
      acc2[t][0] = bv;
      acc2[t][1] = bv;
    }

    #pragma unroll
    for (int kb2 = 0; kb2 < 4; ++kb2) {
      bf16x8 h0 = hreg[kb2][0];
      bf16x8 h1 = hreg[kb2][1];
      #pragma unroll
      for (int t = 0; t < 4; ++t) {
        bf16x8 af = *(const bf16x8*)(w2p + (kb2 * 4 + t) * 512);
        acc2[t][0] = MFMA16(af, h0, acc2[t][0]);
        acc2[t][1] = MFMA16(af, h1, acc2[t][1]);
      }
      __builtin_amdgcn_sched_barrier(0);   // keep W2 in-flight bounded (R13-proven)
    }

    // epilogue 2: LN over n=64 per edge-group, GELU, dot with W3, +b3, store
    {
      float s0 = 0.f, ss0 = 0.f, s1 = 0.f, ss1 = 0.f;
      #pragma unroll
      for (int t = 0; t < 4; ++t)
        #pragma unroll
        for (int j = 0; j < 4; ++j) {
          float v0 = acc2[t][0][j]; s0 += v0; ss0 += v0 * v0;
          float v1 = acc2[t][1][j]; s1 += v1; ss1 += v1 * v1;
        }
      s0  += __shfl_xor(s0, 16);  s0  += __shfl_xor(s0, 32);
      ss0 += __shfl_xor(ss0, 16); ss0 += __shfl_xor(ss0, 32);
      s1  += __shfl_xor(s1, 16);  s1  += __shfl_xor(s1, 32);
      ss1 += __shfl_xor(ss1, 16); ss1 += __shfl_xor(ss1, 32);
      float mu0 = s0 * 0.015625f, mu1 = s1 * 0.015625f;
      float va0 = ss0 * 0.015625f - mu0 * mu0;
      float va1 = ss1 * 0.015625f - mu1 * mu1;
      va0 = (va0 > 0.f) ? va0 : 0.f;
      va1 = (va1 > 0.f) ? va1 : 0.f;
      float rs0 = __builtin_amdgcn_rsqf(va0 + 1e-5f);
      float rs1 = __builtin_amdgcn_rsqf(va1 + 1e-5f);

      float dot0 = 0.f, dot1 = 0.f;
      #pragma unroll
      for (int t = 0; t < 4; ++t) {
        f32x4 gv = *(const f32x4*)(g2s + t * 16 + q * 4);
        f32x4 ev = *(const f32x4*)(e2s + t * 16 + q * 4);
        f32x4 wv = *(const f32x4*)(w3s + t * 16 + q * 4);
        #pragma unroll
        for (int j = 0; j < 4; ++j) {
          float z0 = __builtin_fmaf((acc2[t][0][j] - mu0) * rs0, gv[j], ev[j]);
          float z1 = __builtin_fmaf((acc2[t][1][j] - mu1) * rs1, gv[j], ev[j]);
          dot0 = __builtin_fmaf(gelu_fast(z0), wv[j], dot0);
          dot1 = __builtin_fmaf(gelu_fast(z1), wv[j], dot1);
        }
      }
      dot0 += __shfl_xor(dot0, 16); dot0 += __shfl_xor(dot0, 32);
      dot1 += __shfl_xor(dot1, 16); dot1 += __shfl_xor(dot1, 32);
      if (q == 0) {
        float bias3 = b3s[0];
        if (r0 < E)      out[r0]      = dot0 + bias3;
        if (r0 + 16 < E) out[r0 + 16] = dot1 + bias3;
      }
    }
  }
}

extern "C" void kernel_launch(void* const* d_in, const int* in_sizes, int n_in,
                              void* d_out, int out_size, void* d_ws, size_t ws_size,
                              hipStream_t stream) {
  const float* drug = (const float*)d_in[0];
  const float* dis  = (const float*)d_in[1];
  const int*   src  = (const int*)d_in[2];
  const int*   dst  = (const int*)d_in[3];
  const float* W1   = (const float*)d_in[4];
  const float* b1   = (const float*)d_in[5];
  const float* g1   = (const float*)d_in[6];
  const float* be1  = (const float*)d_in[7];
  const float* W2   = (const float*)d_in[8];
  const float* b2   = (const float*)d_in[9];
  const float* g2   = (const float*)d_in[10];
  const float* be2  = (const float*)d_in[11];
  const float* W3   = (const float*)d_in[12];
  const float* b3   = (const float*)d_in[13];
  float* out = (float*)d_out;

  const int E      = in_sizes[2];
  const int ndrug8 = in_sizes[0] / 8;
  const int ndis8  = in_sizes[1] / 8;
  const int ntiles = (E + 255) / 256;      // 256-edge tiles (8 waves x 32 edges)

  short* w1i   = (short*)d_ws;             // 32768 shorts (full LDS image)
  short* w2L   = w1i + 32768;              // 8192 shorts (W2 lane-linear)
  short* drugb = w2L + 8192;               // bf16 feature tables
  short* disb  = drugb + (size_t)ndrug8 * 8;

  (void)hipFuncSetAttribute((const void*)mlp_fused,
                            hipFuncAttributeMaxDynamicSharedMemorySize, SMEM_BYTES);

  prep_weights<<<dim3(160), dim3(256), 0, stream>>>(W1, W2, w1i, w2L);
  prep_feats<<<dim3((ndrug8 + 255) / 256), dim3(256), 0, stream>>>(drug, drugb, ndrug8);
  prep_feats<<<dim3((ndis8 + 255) / 256), dim3(256), 0, stream>>>(dis, disb, ndis8);

  int grid = 512;
  if (ntiles < grid) grid = ntiles;
  mlp_fused<<<dim3(grid), dim3(512), SMEM_BYTES, stream>>>(
      drugb, disb, src, dst, w1i, w2L,
      b1, g1, be1, b2, g2, be2, W3, b3, out, E, ntiles);
}